// Round 1
// 235.526 us; speedup vs baseline: 1.0409x; 1.0409x over previous
//
#include <hip/hip_runtime.h>
#include <cstdint>
#include <cstddef>

// x[B=32, T=4096, N=256] fp32 -> z same shape.
// Refractory scan: spike at step t iff x>0 and t >= na; then na = t+6.
// Entry state q==k  <=>  first k steps of chunk blocked (na=k). q in [0,5].
//
// R1: occupancy was the bottleneck (10%, 1 block/CU, 4 waves/CU). Shrink
// per-thread chunk CC 128->32 and pack 16 chunks per 1024-thread block:
// grid stays 256 (1 block/CU) but 16 waves/CU now stream the same bytes.
// Chain length (PG=8) and message protocol unchanged.
#define BB 32
#define TT 4096
#define NNV 64        // float4 groups per row (N=256)
#define CC 32         // chunk length (per-thread scan)
#define PSUB 16       // chunks handled per block (one per 64-thread wave)
#define PG 8          // chunk-groups per chain: T / (CC*PSUB) = 8
#define MSG_WORDS 32  // 256 chains * 4-bit state / 8 per u32

__global__ __launch_bounds__(1024) void refrac_fused(const float* __restrict__ x,
                                                     float* __restrict__ z,
                                                     uint32_t* __restrict__ msg) {
    const int tid = threadIdx.x;
    const int pg = blockIdx.x >> 5;   // chunk-group (time-major dispatch)
    const int b  = blockIdx.x & 31;   // batch
    const int psub = tid >> 6;        // which of the 16 chunks (== wave id)
    const int n4 = tid & 63;          // float4 group along N
    const int p = pg * PSUB + psub;   // absolute chunk index

    const float4* __restrict__ xv = reinterpret_cast<const float4*>(x)
        + ((size_t)b * TT + (size_t)p * CC) * NNV + n4;

    // --- Phase 1: scan chunk for all 6 entry states; stash sign bits ---
    int na[4][6];
    #pragma unroll
    for (int c = 0; c < 4; ++c)
        #pragma unroll
        for (int e = 0; e < 6; ++e) na[c][e] = e;

    uint32_t cur[4] = {0u, 0u, 0u, 0u};  // 32 sign bits per chain

    for (int jb = 0; jb < CC; jb += 8) {
        float4 buf[8];
        #pragma unroll
        for (int u = 0; u < 8; ++u)
            buf[u] = xv[(size_t)(jb + u) * NNV];
        #pragma unroll
        for (int u = 0; u < 8; ++u) {
            const int j = jb + u;          // step within chunk (== bit pos)
            const float4 v = buf[u];
            const float fv[4] = {v.x, v.y, v.z, v.w};
            #pragma unroll
            for (int c = 0; c < 4; ++c) {
                const bool pos = fv[c] > 0.0f;
                cur[c] |= pos ? (1u << j) : 0u;
                #pragma unroll
                for (int e = 0; e < 6; ++e)
                    if (pos & (j >= na[c][e])) na[c][e] = j + 6;
            }
        }
    }

    // Pack exit table (6 nibbles) per chain into LDS.
    __shared__ uint32_t tbl_lds[PSUB][256];  // 16 KB
    __shared__ uint32_t ent_lds[PSUB][64];   // 4 KB (byte-addressed writes)
    __shared__ uint8_t  sout_lds[256];

    #pragma unroll
    for (int c = 0; c < 4; ++c) {
        uint32_t tbl = 0;
        #pragma unroll
        for (int e = 0; e < 6; ++e) {
            int q = na[c][e] - CC;
            q = q > 0 ? q : 0;                 // exit state in [0,5]
            tbl |= (uint32_t)q << (4 * e);
        }
        tbl_lds[psub][n4 * 4 + c] = tbl;
    }
    __syncthreads();

    // --- Phase 2: resolve true entry states (thread n handles chain n) ---
    if (tid < 256) {
        const int n = tid;
        int e = 0;
        if (pg > 0) {
            const uint32_t* inw = msg + ((size_t)b * PG + (pg - 1)) * MSG_WORDS + (n >> 3);
            uint32_t wv;
            // nibble bit3 set (poison 0xA) => not ready; states <=5 are valid
            while ((wv = __hip_atomic_load(inw, __ATOMIC_RELAXED,
                                           __HIP_MEMORY_SCOPE_AGENT)) & 0x88888888u)
                __builtin_amdgcn_s_sleep(1);
            e = (int)((wv >> ((n & 7) * 4)) & 0xFu);
        }
        #pragma unroll
        for (int s = 0; s < PSUB; ++s) {
            reinterpret_cast<uint8_t*>(ent_lds[s])[n] = (uint8_t)e;
            e = (int)((tbl_lds[s][n] >> (4 * e)) & 0xFu);
        }
        sout_lds[n] = (uint8_t)e;              // exit of last chunk in group
    }
    __syncthreads();

    if (pg < PG - 1 && tid < MSG_WORDS) {
        uint32_t wv = 0;
        #pragma unroll
        for (int k = 0; k < 8; ++k)
            wv |= (uint32_t)sout_lds[tid * 8 + k] << (4 * k);
        __hip_atomic_store(msg + ((size_t)b * PG + pg) * MSG_WORDS + tid, wv,
                           __ATOMIC_RELAXED, __HIP_MEMORY_SCOPE_AGENT);
    }

    // --- Phase 3: emit z from register bits + resolved entry ---
    float4* __restrict__ zv = reinterpret_cast<float4*>(z)
        + ((size_t)b * TT + (size_t)p * CC) * NNV + n4;

    const uint32_t e4 = ent_lds[psub][n4];     // 4 entry bytes for chains c=0..3
    int ea[4];
    #pragma unroll
    for (int c = 0; c < 4; ++c) ea[c] = (int)((e4 >> (8 * c)) & 0xFFu);

    for (int j = 0; j < CC; ++j) {
        float o[4];
        #pragma unroll
        for (int c = 0; c < 4; ++c) {
            const bool sp = (((cur[c] >> j) & 1u) != 0u) & (j >= ea[c]);
            if (sp) ea[c] = j + 6;
            o[c] = sp ? 1.0f : 0.0f;
        }
        zv[(size_t)j * NNV] = make_float4(o[0], o[1], o[2], o[3]);
    }
}

extern "C" void kernel_launch(void* const* d_in, const int* in_sizes, int n_in,
                              void* d_out, int out_size, void* d_ws, size_t ws_size,
                              hipStream_t stream) {
    const float* x = (const float*)d_in[0];
    float* z = (float*)d_out;
    uint32_t* msg = (uint32_t*)d_ws;

    // Deterministic "not ready" poison for the message area each call.
    hipMemsetAsync(d_ws, 0xAA, (size_t)BB * PG * MSG_WORDS * sizeof(uint32_t), stream);

    refrac_fused<<<dim3(BB * PG), 1024, 0, stream>>>(x, z, msg);
}